// Round 13
// baseline (45.931 us; speedup 1.0000x reference)
//
#include <hip/hip_runtime.h>
#include <hip/hip_bf16.h>
#include <math.h>
#include <stdint.h>

// SpectralPooling: x (4,32,64,64,64) f32 -> out (4,32,32,32,32) f32.
// Separable: out[bc,k,j,l] = sum_{d,h,w} A[k,d]A[j,h]A[l,w] x[bc,d,h,w],
// A = (32x64) fused DCT64->crop32->IDCT32 matrix.
// R13: k_hw stages each wave's 16-KiB slab into wave-private LDS via
//      global_load_lds (16B width, dense 128-B segments) with both-sides
//      XOR swizzle (inverse-swz global source + swz ds_read_b128), then
//      MFMA stages as in R9. k_d / build_tables are R12-exact.
//
// MFMA conventions (mfma_f32_16x16x32_bf16), HW-verified by R3-R12 passing:
//   A-op: lane m = lane&15, k = 8*(lane>>4)+jj ; B-op same map (k-perm cancels)
//   C/D : col = lane&15, row = 4*(lane>>4)+reg
// Swizzle: byte a (slab-relative) -> a ^ (((a>>8)&7)<<5). For fragment reads
//   at a = (mt*16+lm)*256 + kt*128 + lg*32 this is a ^ ((lm&7)<<5): the 8
//   32-B slots of each 256-B row are permuted per lm -> 2-way LDS bank
//   aliasing (free, m136) instead of 16-way.

#define PI_F 3.14159265358979323846f

typedef __attribute__((ext_vector_type(4))) float f32x4;
typedef __attribute__((ext_vector_type(8))) short bf16x8;

union U16x8 { uint4 q; bf16x8 v; uint32_t w[4]; };

// pair f32 -> packed bf16 (RNE) ; compiles to v_cvt_pk_bf16_f32
__device__ __forceinline__ uint32_t pk(float a, float b) {
    union { __hip_bfloat162 h; uint32_t u; } c;
    c.h = __float22bfloat162_rn(make_float2(a, b));
    return c.u;
}

__device__ __forceinline__ unsigned short bf16r(float x) {
    union { float f; uint32_t u; } c; c.f = x;
    uint32_t r = (c.u + 0x7FFFu + ((c.u >> 16) & 1u)) >> 16;  // RNE (table build only)
    return (unsigned short)r;
}

__device__ __forceinline__ float Aelem(int i, int d) {
    const float s1 = sqrtf(1.0f / 32.0f), s2 = sqrtf(2.0f / 32.0f);
    const float t1 = sqrtf(1.0f / 64.0f), t2 = sqrtf(2.0f / 64.0f);
    float acc = 0.f;
    for (int k = 0; k < 32; ++k) {
        int n1 = ((2 * i + 1) * k) & 127;   // cos(pi*n1/64)
        int n2 = ((2 * d + 1) * k) & 255;   // cos(pi*n2/128)
        float c1 = cosf((float)n1 * (PI_F / 64.0f));
        float c2 = cosf((float)n2 * (PI_F / 128.0f));
        acc += ((k == 0) ? s1 : s2) * ((k == 0) ? t1 : t2) * c1 * c2;
    }
    return acc;
}

// ---- tables: At[64][32] f32 (k_d) + F frag table bf16 (k_hw). 16 blocks. ----
__global__ __launch_bounds__(256) void build_tables(float* __restrict__ At,
                                                    unsigned short* __restrict__ F) {
    int e = blockIdx.x * 256 + threadIdx.x;
    if (e < 2048) {
        int d = e >> 5, i = e & 31;
        At[e] = Aelem(i, d);
    } else if (e < 4096) {
        int f = e - 2048;
        int jj = f & 7, lane = (f >> 3) & 63, tk = f >> 9;
        int tt = tk >> 1, kt = tk & 1;
        int row = tt * 16 + (lane & 15);
        int col = kt * 32 + ((lane >> 4) << 3) + jj;
        F[f] = bf16r(Aelem(row, col));
    }
}

// ---- k_hw: 4 waves/block, one slab per wave, LDS-staged x. ----
// Per wave: Xs 16 KiB (slab, swizzled) + Ut 4 KiB -> 80 KiB/block, 2 blocks/CU.
__global__ __launch_bounds__(256) void k_hw(const float* __restrict__ x,
                                            const unsigned short* __restrict__ F,
                                            unsigned short* __restrict__ w1b) {
    __shared__ __align__(16) char lds_all[4][20480];  // [wave]: 16384 Xs + 4096 Ut

    const int t = threadIdx.x;
    const int wv = t >> 6, ln = t & 63;
    const int lm = ln & 15, lg = ln >> 4;
    const size_t slab = (size_t)blockIdx.x * 4 + wv;

    char* Xs = lds_all[wv];
    unsigned short* ut = (unsigned short*)(lds_all[wv] + 16384);

    // constant B-operand frags
    bf16x8 Ff[2][2];
    {
        const uint4* fp = (const uint4*)F;
        #pragma unroll
        for (int tt = 0; tt < 2; ++tt)
            #pragma unroll
            for (int kt = 0; kt < 2; ++kt) {
                U16x8 u; u.q = fp[(tt * 2 + kt) * 64 + ln];
                Ff[tt][kt] = u.v;
            }
    }

    // ---- stage slab -> LDS: linear dest, inverse-swizzled per-lane source ----
    const char* xb = (const char*)(x + slab * 4096);
    #pragma unroll
    for (int s = 0; s < 16; ++s) {
        uint32_t d = (uint32_t)(s * 1024 + ln * 16);
        uint32_t g = d ^ (((d >> 8) & 7u) << 5);   // involution
        __builtin_amdgcn_global_load_lds(
            (const __attribute__((address_space(1))) uint32_t*)(xb + g),
            (__attribute__((address_space(3))) uint32_t*)(Xs + s * 1024),
            16, 0, 0);
    }
    asm volatile("s_waitcnt vmcnt(0)" ::: "memory");
    __builtin_amdgcn_sched_barrier(0);

    // ---- stage B: U[h][l] = sum_w X[h][w] * A[l][w] (fragments from LDS) ----
    f32x4 accu[4][2];
    #pragma unroll
    for (int mt = 0; mt < 4; ++mt)
        #pragma unroll
        for (int nt = 0; nt < 2; ++nt)
            accu[mt][nt] = (f32x4){0.f, 0.f, 0.f, 0.f};

    #pragma unroll
    for (int mt = 0; mt < 4; ++mt) {
        #pragma unroll
        for (int kt = 0; kt < 2; ++kt) {
            uint32_t a = (uint32_t)((mt * 16 + lm) * 256 + kt * 128 + lg * 32);
            a ^= ((a >> 8) & 7u) << 5;             // = ^ ((lm&7)<<5)
            const float4* fp4 = (const float4*)(Xs + a);  // 2 x ds_read_b128
            float4 A0 = fp4[0], A1 = fp4[1];
            U16x8 xf;
            xf.w[0] = pk(A0.x, A0.y);
            xf.w[1] = pk(A0.z, A0.w);
            xf.w[2] = pk(A1.x, A1.y);
            xf.w[3] = pk(A1.z, A1.w);
            #pragma unroll
            for (int nt = 0; nt < 2; ++nt)
                accu[mt][nt] = __builtin_amdgcn_mfma_f32_16x16x32_bf16(
                    xf.v, Ff[nt][kt], accu[mt][nt], 0, 0, 0);
        }
    }

    // ---- transpose U -> Ut[l][h] (bf16, XOR-swizzled), wave-private ----
    #pragma unroll
    for (int mt = 0; mt < 4; ++mt)
        #pragma unroll
        for (int nt = 0; nt < 2; ++nt) {
            int lo = nt * 16 + lm;               // Ut row (= l)
            int h0 = mt * 16 + (lg << 2);        // 4 consecutive h
            uint32_t w0 = pk(accu[mt][nt][0], accu[mt][nt][1]);
            uint32_t w1v = pk(accu[mt][nt][2], accu[mt][nt][3]);
            uint32_t byte = (uint32_t)(lo * 128 + 2 * h0);
            byte ^= (uint32_t)((lo & 7) << 4);   // bank swizzle
            *(uint2*)((char*)ut + byte) = make_uint2(w0, w1v);
        }
    __builtin_amdgcn_wave_barrier();

    // ---- stage C: O^T[l][j] = sum_h Ut[l][h] * A[j][h] ----
    f32x4 acco[2][2];
    #pragma unroll
    for (int mt = 0; mt < 2; ++mt)
        #pragma unroll
        for (int nt = 0; nt < 2; ++nt)
            acco[mt][nt] = (f32x4){0.f, 0.f, 0.f, 0.f};

    #pragma unroll
    for (int mt = 0; mt < 2; ++mt) {
        #pragma unroll
        for (int kt = 0; kt < 2; ++kt) {
            int lo = mt * 16 + lm;
            uint32_t byte = (uint32_t)(lo * 128 + kt * 64 + (lg << 4));
            byte ^= (uint32_t)((lo & 7) << 4);
            bf16x8 uf = *(const bf16x8*)((const char*)ut + byte);  // ds_read_b128
            #pragma unroll
            for (int nt = 0; nt < 2; ++nt)
                acco[mt][nt] = __builtin_amdgcn_mfma_f32_16x16x32_bf16(
                    uf, Ff[nt][kt], acco[mt][nt], 0, 0, 0);
        }
    }

    // ---- direct packed store: lane owns 4 consecutive l per (mt,nt) ----
    #pragma unroll
    for (int mt = 0; mt < 2; ++mt)
        #pragma unroll
        for (int nt = 0; nt < 2; ++nt) {
            uint32_t u0 = pk(acco[mt][nt][0], acco[mt][nt][1]);
            uint32_t u1 = pk(acco[mt][nt][2], acco[mt][nt][3]);
            int j  = nt * 16 + lm;
            int l0 = mt * 16 + (lg << 2);
            *(uint2*)(w1b + slab * 1024 + j * 32 + l0) = make_uint2(u0, u1);
        }
}

// ---- k_d: R4-exact (measured-best). grid = 128 bc x 2 kh x 4 q = 1024 ----
// out[bc][kh*16+kk][p] = sum_d At[d][kh*16+kk] * w1b[bc][d][p]
__global__ __launch_bounds__(256) void k_d(const unsigned short* __restrict__ w1b,
                                           const float* __restrict__ At,
                                           float* __restrict__ out) {
    const int t = threadIdx.x;
    const int bc = blockIdx.x >> 3;
    const int kh = (blockIdx.x >> 2) & 1;
    const int q  = blockIdx.x & 3;
    const int p  = q * 256 + t;
    const unsigned short* src = w1b + (size_t)bc * 65536 + p;
    float acc[16];
    #pragma unroll
    for (int k = 0; k < 16; ++k) acc[k] = 0.f;
    #pragma unroll 8
    for (int d = 0; d < 64; ++d) {
        uint32_t u = (uint32_t)src[d * 1024];
        float v = __uint_as_float(u << 16);       // bf16 -> f32
        const float* arow = At + d * 32 + kh * 16;  // wave-uniform -> s_load
        #pragma unroll
        for (int k = 0; k < 16; ++k) acc[k] += arow[k] * v;
    }
    float* dst = out + (size_t)bc * 32768 + (size_t)kh * 16384 + p;
    #pragma unroll
    for (int k = 0; k < 16; ++k) dst[k * 1024] = acc[k];
}

extern "C" void kernel_launch(void* const* d_in, const int* in_sizes, int n_in,
                              void* d_out, int out_size, void* d_ws, size_t ws_size,
                              hipStream_t stream) {
    const float* x = (const float*)d_in[0];
    float* out = (float*)d_out;

    float* At           = (float*)d_ws;                           // 8 KiB
    unsigned short* F   = (unsigned short*)((char*)d_ws + 8192);  // 4 KiB
    unsigned short* w1b = (unsigned short*)((char*)d_ws + 16384); // 16 MiB (bf16)

    build_tables<<<16, 256, 0, stream>>>(At, F);
    k_hw<<<2048, 256, 0, stream>>>(x, F, w1b);
    k_d<<<1024, 256, 0, stream>>>(w1b, At, out);
}

// Round 14
// 43.791 us; speedup vs baseline: 1.0489x; 1.0489x over previous
//
#include <hip/hip_runtime.h>
#include <hip/hip_bf16.h>
#include <math.h>
#include <stdint.h>
#include <string.h>

// SpectralPooling: x (4,32,64,64,64) f32 -> out (4,32,32,32,32) f32.
// Separable: out[bc,k,j,l] = sum_{d,h,w} A[k,d]A[j,h]A[l,w] x[bc,d,h,w],
// A = (32x64) fused DCT64->crop32->IDCT32 matrix.
// R14: tables computed on HOST (double cos) and uploaded via one 12-KiB
//      hipMemcpyAsync -> build_tables kernel + one launch gap eliminated.
//      k_hw = R9/R12-exact, k_d = R4-exact (both measured-best).
//
// MFMA conventions (mfma_f32_16x16x32_bf16), HW-verified by R3-R13 passing:
//   A-op: lane m = lane&15, k = 8*(lane>>4)+jj ; B-op same map (k-perm cancels)
//   C/D : col = lane&15, row = 4*(lane>>4)+reg

typedef __attribute__((ext_vector_type(4))) float f32x4;
typedef __attribute__((ext_vector_type(8))) short bf16x8;

union U16x8 { uint4 q; bf16x8 v; uint32_t w[4]; };

// pair f32 -> packed bf16 (RNE) ; compiles to v_cvt_pk_bf16_f32
__device__ __forceinline__ uint32_t pk(float a, float b) {
    union { __hip_bfloat162 h; uint32_t u; } c;
    c.h = __float22bfloat162_rn(make_float2(a, b));
    return c.u;
}

// ---- k_hw: 4 waves/block, one slab per wave, wave-private LDS only.
// launch_bounds(256,4): cap 128 VGPR -> 4 waves/SIMD (16 waves/CU).
__global__ __launch_bounds__(256, 4) void k_hw(const float* __restrict__ x,
                                               const unsigned short* __restrict__ F,
                                               unsigned short* __restrict__ w1b) {
    __shared__ unsigned short Ut[4][2048];   // per-wave Ut[l][h] bf16, XOR-swizzled

    const int t = threadIdx.x;
    const int wv = t >> 6, ln = t & 63;
    const int lm = ln & 15, lg = ln >> 4;
    const size_t slab = (size_t)blockIdx.x * 4 + wv;

    // constant B-operand frags
    bf16x8 Ff[2][2];
    {
        const uint4* fp = (const uint4*)F;
        #pragma unroll
        for (int tt = 0; tt < 2; ++tt)
            #pragma unroll
            for (int kt = 0; kt < 2; ++kt) {
                U16x8 u; u.q = fp[(tt * 2 + kt) * 64 + ln];
                Ff[tt][kt] = u.v;
            }
    }

    // ---- issue all 16 x-loads up front ----
    const float* xs = x + slab * 4096;
    uint4 raw[16];
    #pragma unroll
    for (int mt = 0; mt < 4; ++mt)
        #pragma unroll
        for (int kt = 0; kt < 2; ++kt) {
            const uint4* p = (const uint4*)(xs + (mt * 16 + lm) * 64 + kt * 32 + (lg << 3));
            raw[(mt * 2 + kt) * 2 + 0] = p[0];
            raw[(mt * 2 + kt) * 2 + 1] = p[1];
        }

    // ---- stage B: U[h][l] = sum_w X[h][w] * A[l][w] ----
    f32x4 accu[4][2];
    #pragma unroll
    for (int mt = 0; mt < 4; ++mt)
        #pragma unroll
        for (int nt = 0; nt < 2; ++nt)
            accu[mt][nt] = (f32x4){0.f, 0.f, 0.f, 0.f};

    #pragma unroll
    for (int mt = 0; mt < 4; ++mt) {
        #pragma unroll
        for (int kt = 0; kt < 2; ++kt) {
            const float* f0 = (const float*)&raw[(mt * 2 + kt) * 2];
            U16x8 xf;
            #pragma unroll
            for (int e = 0; e < 4; ++e)
                xf.w[e] = pk(f0[2 * e], f0[2 * e + 1]);   // v_cvt_pk_bf16_f32
            #pragma unroll
            for (int nt = 0; nt < 2; ++nt)
                accu[mt][nt] = __builtin_amdgcn_mfma_f32_16x16x32_bf16(
                    xf.v, Ff[nt][kt], accu[mt][nt], 0, 0, 0);
        }
    }

    // ---- transpose U -> Ut[l][h] (bf16, XOR-swizzled), wave-private ----
    unsigned short* ut = Ut[wv];
    #pragma unroll
    for (int mt = 0; mt < 4; ++mt)
        #pragma unroll
        for (int nt = 0; nt < 2; ++nt) {
            int lo = nt * 16 + lm;               // Ut row (= l)
            int h0 = mt * 16 + (lg << 2);        // 4 consecutive h
            uint32_t w0 = pk(accu[mt][nt][0], accu[mt][nt][1]);
            uint32_t w1v = pk(accu[mt][nt][2], accu[mt][nt][3]);
            uint32_t byte = (uint32_t)(lo * 128 + 2 * h0);
            byte ^= (uint32_t)((lo & 7) << 4);   // bank swizzle
            *(uint2*)((char*)ut + byte) = make_uint2(w0, w1v);
        }
    __builtin_amdgcn_wave_barrier();

    // ---- stage C: O^T[l][j] = sum_h Ut[l][h] * A[j][h] ----
    f32x4 acco[2][2];
    #pragma unroll
    for (int mt = 0; mt < 2; ++mt)
        #pragma unroll
        for (int nt = 0; nt < 2; ++nt)
            acco[mt][nt] = (f32x4){0.f, 0.f, 0.f, 0.f};

    #pragma unroll
    for (int mt = 0; mt < 2; ++mt) {
        #pragma unroll
        for (int kt = 0; kt < 2; ++kt) {
            int lo = mt * 16 + lm;
            uint32_t byte = (uint32_t)(lo * 128 + kt * 64 + (lg << 4));
            byte ^= (uint32_t)((lo & 7) << 4);
            bf16x8 uf = *(const bf16x8*)((const char*)ut + byte);  // ds_read_b128
            #pragma unroll
            for (int nt = 0; nt < 2; ++nt)
                acco[mt][nt] = __builtin_amdgcn_mfma_f32_16x16x32_bf16(
                    uf, Ff[nt][kt], acco[mt][nt], 0, 0, 0);
        }
    }

    // ---- direct packed store: lane owns 4 consecutive l per (mt,nt) ----
    #pragma unroll
    for (int mt = 0; mt < 2; ++mt)
        #pragma unroll
        for (int nt = 0; nt < 2; ++nt) {
            uint32_t u0 = pk(acco[mt][nt][0], acco[mt][nt][1]);
            uint32_t u1 = pk(acco[mt][nt][2], acco[mt][nt][3]);
            int j  = nt * 16 + lm;
            int l0 = mt * 16 + (lg << 2);
            *(uint2*)(w1b + slab * 1024 + j * 32 + l0) = make_uint2(u0, u1);
        }
}

// ---- k_d: R4-exact (measured-best). grid = 128 bc x 2 kh x 4 q = 1024 ----
// out[bc][kh*16+kk][p] = sum_d At[d][kh*16+kk] * w1b[bc][d][p]
__global__ __launch_bounds__(256) void k_d(const unsigned short* __restrict__ w1b,
                                           const float* __restrict__ At,
                                           float* __restrict__ out) {
    const int t = threadIdx.x;
    const int bc = blockIdx.x >> 3;
    const int kh = (blockIdx.x >> 2) & 1;
    const int q  = blockIdx.x & 3;
    const int p  = q * 256 + t;
    const unsigned short* src = w1b + (size_t)bc * 65536 + p;
    float acc[16];
    #pragma unroll
    for (int k = 0; k < 16; ++k) acc[k] = 0.f;
    #pragma unroll 8
    for (int d = 0; d < 64; ++d) {
        uint32_t u = (uint32_t)src[d * 1024];
        float v = __uint_as_float(u << 16);       // bf16 -> f32
        const float* arow = At + d * 32 + kh * 16;  // wave-uniform -> s_load
        #pragma unroll
        for (int k = 0; k < 16; ++k) acc[k] += arow[k] * v;
    }
    float* dst = out + (size_t)bc * 32768 + (size_t)kh * 16384 + p;
    #pragma unroll
    for (int k = 0; k < 16; ++k) dst[k * 1024] = acc[k];
}

// ---- host-side table build (runs at capture/correctness call only) ----
struct Tables { float At[2048]; unsigned short F[2048]; };  // 12288 B
static Tables h_tabs;

static unsigned short bf16r_host(float x) {
    uint32_t u; memcpy(&u, &x, 4);
    uint32_t r = (u + 0x7FFFu + ((u >> 16) & 1u)) >> 16;  // RNE
    return (unsigned short)r;
}

extern "C" void kernel_launch(void* const* d_in, const int* in_sizes, int n_in,
                              void* d_out, int out_size, void* d_ws, size_t ws_size,
                              hipStream_t stream) {
    const float* x = (const float*)d_in[0];
    float* out = (float*)d_out;

    float* At           = (float*)d_ws;                           // 8 KiB
    unsigned short* F   = (unsigned short*)((char*)d_ws + 8192);  // 4 KiB
    unsigned short* w1b = (unsigned short*)((char*)d_ws + 16384); // 16 MiB (bf16)

    // A[i][d] = sum_{k<32} s32(k)s64(k) cos(pi(2i+1)k/64) cos(pi(2d+1)k/128)
    // (recomputed every call -- deterministic, no static guards; replays skip host code)
    float Afull[32][64];
    {
        const double s1 = sqrt(1.0 / 32.0), s2 = sqrt(2.0 / 32.0);
        const double t1 = sqrt(1.0 / 64.0), t2 = sqrt(2.0 / 64.0);
        for (int i = 0; i < 32; ++i)
            for (int d = 0; d < 64; ++d) {
                double acc = 0.0;
                for (int k = 0; k < 32; ++k) {
                    double c1 = cos(M_PI * (double)((2 * i + 1) * k) / 64.0);
                    double c2 = cos(M_PI * (double)((2 * d + 1) * k) / 128.0);
                    acc += ((k == 0) ? s1 : s2) * ((k == 0) ? t1 : t2) * c1 * c2;
                }
                Afull[i][d] = (float)acc;
            }
        for (int d = 0; d < 64; ++d)
            for (int i = 0; i < 32; ++i)
                h_tabs.At[d * 32 + i] = Afull[i][d];
        // F frag table: F[((tt*2+kt)*64+lane)*8+jj] = bf16(A[tt*16+(lane&15)][kt*32+8*(lane>>4)+jj])
        for (int tt = 0; tt < 2; ++tt)
            for (int kt = 0; kt < 2; ++kt)
                for (int lane = 0; lane < 64; ++lane)
                    for (int jj = 0; jj < 8; ++jj) {
                        int row = tt * 16 + (lane & 15);
                        int col = kt * 32 + ((lane >> 4) << 3) + jj;
                        h_tabs.F[((tt * 2 + kt) * 64 + lane) * 8 + jj] =
                            bf16r_host(Afull[row][col]);
                    }
    }
    hipMemcpyAsync(d_ws, &h_tabs, sizeof(Tables), hipMemcpyHostToDevice, stream);

    k_hw<<<2048, 256, 0, stream>>>(x, F, w1b);
    k_d<<<1024, 256, 0, stream>>>(w1b, At, out);
}

// Round 15
// 40.781 us; speedup vs baseline: 1.1263x; 1.0738x over previous
//
#include <hip/hip_runtime.h>
#include <hip/hip_bf16.h>
#include <stdint.h>

// SpectralPooling: x (4,32,64,64,64) f32 -> out (4,32,32,32,32) f32.
// Separable: out[bc,k,j,l] = sum_{d,h,w} A[k,d]A[j,h]A[l,w] x[bc,d,h,w],
// A = (32x64) fused DCT64->crop32->IDCT32 matrix.
// R15: tables are COMPILE-TIME constexpr (quadrant-reduced Taylor cos +
//      Newton sqrt, exact integer angle reduction) emitted as __constant__
//      -> no build kernel, no H2D memcpy node; stream = 2 kernel launches.
//      k_hw = R9-exact structure (F frags now f32->pk'd in-kernel, same RNE
//      bf16 values), k_d = R4-exact.
//
// MFMA conventions (mfma_f32_16x16x32_bf16), HW-verified by R3-R14 passing:
//   A-op: lane m = lane&15, k = 8*(lane>>4)+jj ; B-op same map (k-perm cancels)
//   C/D : col = lane&15, row = 4*(lane>>4)+reg

typedef __attribute__((ext_vector_type(4))) float f32x4;
typedef __attribute__((ext_vector_type(8))) short bf16x8;

union U16x8 { uint4 q; bf16x8 v; uint32_t w[4]; };

// pair f32 -> packed bf16 (RNE) ; compiles to v_cvt_pk_bf16_f32
__device__ __forceinline__ uint32_t pk(float a, float b) {
    union { __hip_bfloat162 h; uint32_t u; } c;
    c.h = __float22bfloat162_rn(make_float2(a, b));
    return c.u;
}

// ================= compile-time tables =================
struct Tabs {
    float At[2048];   // At[d*32+i] = A[i][d]           (k_d, wave-uniform s_load)
    float Ff[2048];   // Ff[((tt*2+kt)*64+lane)*8+jj] = A[tt*16+(lane&15)][kt*32+8*(lane>>4)+jj]
};

constexpr double kPI = 3.14159265358979323846;

constexpr double csqrt(double v) {
    double g = v;
    for (int i = 0; i < 64; ++i) g = 0.5 * (g + v / g);
    return g;
}

constexpr Tabs make_tabs() {
    // ct[n] = cos(pi*n/128), n in [0,256): quadrant-reduce + 12-term Taylor
    double ct[256] = {};
    for (int n = 0; n < 256; ++n) {
        int m = n;
        if (m > 128) m = 256 - m;
        double sgn = 1.0;
        if (m > 64) { m = 128 - m; sgn = -1.0; }
        double x = kPI * (double)m / 128.0;
        double x2 = x * x, term = 1.0, sum = 1.0;
        for (int i = 1; i <= 12; ++i) {
            term *= -x2 / (double)((2 * i - 1) * (2 * i));
            sum += term;
        }
        ct[n] = sgn * sum;
    }
    // w[k] = s32(k)*s64(k)
    double w[32] = {};
    {
        double sA0 = csqrt(1.0 / 32.0), sA = csqrt(2.0 / 32.0);
        double sB0 = csqrt(1.0 / 64.0), sB = csqrt(2.0 / 64.0);
        for (int k = 0; k < 32; ++k)
            w[k] = (k == 0 ? sA0 : sA) * (k == 0 ? sB0 : sB);
    }
    Tabs T{};
    // At[d*32+i] = A[i][d] = sum_k w[k] cos(pi(2i+1)k/64) cos(pi(2d+1)k/128)
    for (int i = 0; i < 32; ++i) {
        int a2 = 2 * i + 1;
        for (int d = 0; d < 64; ++d) {
            int b2 = 2 * d + 1;
            double acc = 0.0;
            for (int k = 0; k < 32; ++k) {
                int n1 = (2 * (a2 * k)) & 255;   // cos(pi*(a2 k)/64) = ct[(2 a2 k) mod 256]
                int n2 = (b2 * k) & 255;         // cos(pi*(b2 k)/128)
                acc += w[k] * ct[n1] * ct[n2];
            }
            T.At[d * 32 + i] = (float)acc;
        }
    }
    // Ff frag table (f32; kernel converts to bf16 with v_cvt_pk RNE)
    for (int tt = 0; tt < 2; ++tt)
        for (int kt = 0; kt < 2; ++kt)
            for (int lane = 0; lane < 64; ++lane)
                for (int jj = 0; jj < 8; ++jj) {
                    int row = tt * 16 + (lane & 15);
                    int col = kt * 32 + ((lane >> 4) << 3) + jj;
                    T.Ff[((tt * 2 + kt) * 64 + lane) * 8 + jj] = T.At[col * 32 + row];
                }
    return T;
}

constexpr Tabs kTabs = make_tabs();
__constant__ Tabs g_tabs = kTabs;

// ---- k_hw: 4 waves/block, one slab per wave, wave-private LDS only.
// launch_bounds(256,4): cap 128 VGPR -> 4 waves/SIMD (16 waves/CU).
__global__ __launch_bounds__(256, 4) void k_hw(const float* __restrict__ x,
                                               unsigned short* __restrict__ w1b) {
    __shared__ unsigned short Ut[4][2048];   // per-wave Ut[l][h] bf16, XOR-swizzled

    const int t = threadIdx.x;
    const int wv = t >> 6, ln = t & 63;
    const int lm = ln & 15, lg = ln >> 4;
    const size_t slab = (size_t)blockIdx.x * 4 + wv;

    // constant B-operand frags (f32 table -> pk to bf16, identical RNE values)
    bf16x8 Ff[2][2];
    #pragma unroll
    for (int tt = 0; tt < 2; ++tt)
        #pragma unroll
        for (int kt = 0; kt < 2; ++kt) {
            const float4* fp4 = (const float4*)(g_tabs.Ff + ((tt * 2 + kt) * 64 + ln) * 8);
            float4 fa = fp4[0], fb = fp4[1];
            U16x8 u;
            u.w[0] = pk(fa.x, fa.y);
            u.w[1] = pk(fa.z, fa.w);
            u.w[2] = pk(fb.x, fb.y);
            u.w[3] = pk(fb.z, fb.w);
            Ff[tt][kt] = u.v;
        }

    // ---- issue all 16 x-loads up front ----
    const float* xs = x + slab * 4096;
    uint4 raw[16];
    #pragma unroll
    for (int mt = 0; mt < 4; ++mt)
        #pragma unroll
        for (int kt = 0; kt < 2; ++kt) {
            const uint4* p = (const uint4*)(xs + (mt * 16 + lm) * 64 + kt * 32 + (lg << 3));
            raw[(mt * 2 + kt) * 2 + 0] = p[0];
            raw[(mt * 2 + kt) * 2 + 1] = p[1];
        }

    // ---- stage B: U[h][l] = sum_w X[h][w] * A[l][w] ----
    f32x4 accu[4][2];
    #pragma unroll
    for (int mt = 0; mt < 4; ++mt)
        #pragma unroll
        for (int nt = 0; nt < 2; ++nt)
            accu[mt][nt] = (f32x4){0.f, 0.f, 0.f, 0.f};

    #pragma unroll
    for (int mt = 0; mt < 4; ++mt) {
        #pragma unroll
        for (int kt = 0; kt < 2; ++kt) {
            const float* f0 = (const float*)&raw[(mt * 2 + kt) * 2];
            U16x8 xf;
            #pragma unroll
            for (int e = 0; e < 4; ++e)
                xf.w[e] = pk(f0[2 * e], f0[2 * e + 1]);   // v_cvt_pk_bf16_f32
            #pragma unroll
            for (int nt = 0; nt < 2; ++nt)
                accu[mt][nt] = __builtin_amdgcn_mfma_f32_16x16x32_bf16(
                    xf.v, Ff[nt][kt], accu[mt][nt], 0, 0, 0);
        }
    }

    // ---- transpose U -> Ut[l][h] (bf16, XOR-swizzled), wave-private ----
    unsigned short* ut = Ut[wv];
    #pragma unroll
    for (int mt = 0; mt < 4; ++mt)
        #pragma unroll
        for (int nt = 0; nt < 2; ++nt) {
            int lo = nt * 16 + lm;               // Ut row (= l)
            int h0 = mt * 16 + (lg << 2);        // 4 consecutive h
            uint32_t w0 = pk(accu[mt][nt][0], accu[mt][nt][1]);
            uint32_t w1v = pk(accu[mt][nt][2], accu[mt][nt][3]);
            uint32_t byte = (uint32_t)(lo * 128 + 2 * h0);
            byte ^= (uint32_t)((lo & 7) << 4);   // bank swizzle
            *(uint2*)((char*)ut + byte) = make_uint2(w0, w1v);
        }
    __builtin_amdgcn_wave_barrier();

    // ---- stage C: O^T[l][j] = sum_h Ut[l][h] * A[j][h] ----
    f32x4 acco[2][2];
    #pragma unroll
    for (int mt = 0; mt < 2; ++mt)
        #pragma unroll
        for (int nt = 0; nt < 2; ++nt)
            acco[mt][nt] = (f32x4){0.f, 0.f, 0.f, 0.f};

    #pragma unroll
    for (int mt = 0; mt < 2; ++mt) {
        #pragma unroll
        for (int kt = 0; kt < 2; ++kt) {
            int lo = mt * 16 + lm;
            uint32_t byte = (uint32_t)(lo * 128 + kt * 64 + (lg << 4));
            byte ^= (uint32_t)((lo & 7) << 4);
            bf16x8 uf = *(const bf16x8*)((const char*)ut + byte);  // ds_read_b128
            #pragma unroll
            for (int nt = 0; nt < 2; ++nt)
                acco[mt][nt] = __builtin_amdgcn_mfma_f32_16x16x32_bf16(
                    uf, Ff[nt][kt], acco[mt][nt], 0, 0, 0);
        }
    }

    // ---- direct packed store: lane owns 4 consecutive l per (mt,nt) ----
    #pragma unroll
    for (int mt = 0; mt < 2; ++mt)
        #pragma unroll
        for (int nt = 0; nt < 2; ++nt) {
            uint32_t u0 = pk(acco[mt][nt][0], acco[mt][nt][1]);
            uint32_t u1 = pk(acco[mt][nt][2], acco[mt][nt][3]);
            int j  = nt * 16 + lm;
            int l0 = mt * 16 + (lg << 2);
            *(uint2*)(w1b + slab * 1024 + j * 32 + l0) = make_uint2(u0, u1);
        }
}

// ---- k_d: R4-exact (measured-best). grid = 128 bc x 2 kh x 4 q = 1024 ----
// out[bc][kh*16+kk][p] = sum_d At[d][kh*16+kk] * w1b[bc][d][p]
__global__ __launch_bounds__(256) void k_d(const unsigned short* __restrict__ w1b,
                                           float* __restrict__ out) {
    const int t = threadIdx.x;
    const int bc = blockIdx.x >> 3;
    const int kh = (blockIdx.x >> 2) & 1;
    const int q  = blockIdx.x & 3;
    const int p  = q * 256 + t;
    const unsigned short* src = w1b + (size_t)bc * 65536 + p;
    float acc[16];
    #pragma unroll
    for (int k = 0; k < 16; ++k) acc[k] = 0.f;
    #pragma unroll 8
    for (int d = 0; d < 64; ++d) {
        uint32_t u = (uint32_t)src[d * 1024];
        float v = __uint_as_float(u << 16);            // bf16 -> f32
        const float* arow = g_tabs.At + d * 32 + kh * 16;  // wave-uniform -> s_load
        #pragma unroll
        for (int k = 0; k < 16; ++k) acc[k] += arow[k] * v;
    }
    float* dst = out + (size_t)bc * 32768 + (size_t)kh * 16384 + p;
    #pragma unroll
    for (int k = 0; k < 16; ++k) dst[k * 1024] = acc[k];
}

extern "C" void kernel_launch(void* const* d_in, const int* in_sizes, int n_in,
                              void* d_out, int out_size, void* d_ws, size_t ws_size,
                              hipStream_t stream) {
    const float* x = (const float*)d_in[0];
    float* out = (float*)d_out;
    unsigned short* w1b = (unsigned short*)d_ws;   // 16 MiB (bf16)

    k_hw<<<2048, 256, 0, stream>>>(x, w1b);
    k_d<<<1024, 256, 0, stream>>>(w1b, out);
}